// Round 18
// baseline (237.168 us; speedup 1.0000x reference)
//
#include <hip/hip_runtime.h>

typedef __bf16 bf16_t;
typedef __bf16 bf16x8 __attribute__((ext_vector_type(8)));
typedef float f32x4 __attribute__((ext_vector_type(4)));

#define INF 256
#define HF 128
#define NPB 8           // nodes per gather block (8KB LDS -> up to 16 blocks/CU)
#define NH (NPB / 2)    // rows per parity plane
#define CHP 16          // edges per parity-plane per chunk (32 total)
#define SLMASK 0x00FFFFFF
#define SCAN_STRIDE 512

__device__ inline float2 bf2_to_f2(unsigned v) {
    float lo = __uint_as_float(v << 16);
    float hi = __uint_as_float(v & 0xffff0000u);
    return make_float2(lo, hi);
}
__device__ inline unsigned f2_to_bf2(float a, float b) {
    __bf16 x = (__bf16)a, y = (__bf16)b;
    unsigned short ux = __builtin_bit_cast(unsigned short, x);
    unsigned short uy = __builtin_bit_cast(unsigned short, y);
    return (unsigned)ux | ((unsigned)uy << 16);
}

// ---- merged init: zero region + roots[g] ----
__global__ void k_init(const int* __restrict__ batch, int* __restrict__ roots,
                       int* __restrict__ Z, int N, int B, int zwords) {
    int i = blockIdx.x * blockDim.x + threadIdx.x;
    if (i < zwords) Z[i] = 0;
    if (i == 0) roots[B] = N;
    if (i < N) {
        if (i == 0) roots[batch[0]] = 0;
        else if (batch[i] != batch[i - 1]) roots[batch[i]] = i;
    }
}

// two W1 matrices (256x128 f32) -> bf16 MFMA B-fragment order, 32768 each
__global__ void k_wswz2(const float* __restrict__ tw1, const float* __restrict__ bw1,
                        bf16_t* __restrict__ o) {
    int idx = blockIdx.x * blockDim.x + threadIdx.x;
    if (idx >= 65536) return;
    const float* W = (idx < 32768) ? tw1 : bw1;
    bf16_t* out = o + (idx & 32768);
    int i = idx & 32767;
    int j  = i & 7;
    int l  = (i >> 3) & 63;
    int t  = i >> 9;          // kk*8 + n
    int n  = t & 7;
    int kk = t >> 3;
    int k  = kk * 32 + ((l >> 4) << 3) + j;
    int c  = (n << 4) + (l & 15);
    out[i] = (bf16_t)W[k * HF + c];
}

// in-degree for both directions. TD: d=dst. BU: d=src. Virtual edge N->root.
__global__ void k_degboth(const int* __restrict__ src, const int* __restrict__ dst,
                          const int* __restrict__ roots, int* __restrict__ indeg,
                          int E, int B, int N, int nv) {
    int e = blockIdx.x * blockDim.x + threadIdx.x;
    if (e >= E + B) return;
    int a, b;
    if (e < E) { a = src[e]; b = dst[e]; }
    else       { a = N;      b = roots[e - E]; }
    atomicAdd(&indeg[b], 1);        // TD
    atomicAdd(&indeg[nv + a], 1);   // BU
}

__global__ void k_dinvboth(const int* __restrict__ indeg, float* __restrict__ dinv, int n2) {
    int i = blockIdx.x * blockDim.x + threadIdx.x;
    if (i < n2) dinv[i] = rsqrtf(1.0f + (float)indeg[i]);  // +1 self-loop
}

// per-256-chunk sums
__global__ __launch_bounds__(256) void k_scan1(const int* __restrict__ indeg, int* __restrict__ bsum, int nv) {
    int dir = blockIdx.y;
    __shared__ int s[256];
    int t = threadIdx.x;
    int v = blockIdx.x * 256 + t;
    s[t] = (v < nv) ? indeg[dir * nv + v] : 0;
    __syncthreads();
    for (int off = 128; off > 0; off >>= 1) {
        if (t < off) s[t] += s[t + off];
        __syncthreads();
    }
    if (t == 0) bsum[dir * SCAN_STRIDE + blockIdx.x] = s[0];
}

// exclusive scan of block sums (nblk <= 512)
__global__ __launch_bounds__(512) void k_scan2(int* __restrict__ bsum, int nblk) {
    int dir = blockIdx.y;
    int* p = bsum + dir * SCAN_STRIDE;
    __shared__ int s[512];
    int t = threadIdx.x;
    int v = (t < nblk) ? p[t] : 0;
    s[t] = v;
    __syncthreads();
    for (int off = 1; off < 512; off <<= 1) {
        int u = (t >= off) ? s[t - off] : 0;
        __syncthreads();
        s[t] += u;
        __syncthreads();
    }
    if (t < nblk) p[t] = s[t] - v;  // exclusive
}

// per-element exclusive offsets + cursor copy
__global__ __launch_bounds__(256) void k_scan3(const int* __restrict__ indeg, const int* __restrict__ bsum,
                                               int* __restrict__ off, int* __restrict__ cursor,
                                               int nv, int total) {
    int dir = blockIdx.y;
    __shared__ int s[256];
    int t = threadIdx.x;
    int v0 = blockIdx.x * 256 + t;
    int val = (v0 < nv) ? indeg[dir * nv + v0] : 0;
    s[t] = val;
    __syncthreads();
    for (int o = 1; o < 256; o <<= 1) {
        int u = (t >= o) ? s[t - o] : 0;
        __syncthreads();
        s[t] += u;
        __syncthreads();
    }
    int excl = s[t] - val + bsum[dir * SCAN_STRIDE + blockIdx.x];
    if (v0 < nv) {
        off[dir * (nv + 1) + v0] = excl;
        cursor[dir * nv + v0] = excl;
    }
    if (blockIdx.x == 0 && t == 0) off[dir * (nv + 1) + nv] = total;
}

// fill packed slot lists for both directions: word = src | ((owner & (NPB-1)) << 24)
__global__ void k_fill(const int* __restrict__ src, const int* __restrict__ dst,
                       const int* __restrict__ roots, int* __restrict__ cursor,
                       int* __restrict__ slots,
                       int E, int B, int N, int nv) {
    int e = blockIdx.x * blockDim.x + threadIdx.x;
    if (e >= E + B) return;
    int EB = E + B;
    int a, b;
    if (e < E) { a = src[e]; b = dst[e]; }
    else       { a = N;      b = roots[e - E]; }
    int p = atomicAdd(&cursor[b], 1);            // TD: owner b, source a
    slots[p] = a | ((b & (NPB - 1)) << 24);
    p = atomicAdd(&cursor[nv + a], 1);           // BU: owner a, source b
    slots[EB + p] = b | ((a & (NPB - 1)) << 24);
}

// Dual-direction MFMA GEMM1: 128 rows/block (8 waves). W staged per-kk into a
// DOUBLE-buffered 32KB LDS slab (conflict-free 16B/lane stride).
__global__ __launch_bounds__(512) void k_gemm1both(
    const float* __restrict__ x, const float* __restrict__ emb,
    const bf16_t* __restrict__ WfTD, const bf16_t* __restrict__ WfBU,
    const float* __restrict__ dinvTD, const float* __restrict__ dinvBU,
    bf16_t* __restrict__ rawsTD, bf16_t* __restrict__ rawsBU,
    int nv, int N)
{
    __shared__ bf16_t WS[2 * 8192];   // 2 x 16 KB; f4-unit idx: d*512 + n*64 + lane
    int lane = threadIdx.x & 63;
    int wave = threadIdx.x >> 6;        // 0..7
    int rowbase = blockIdx.x * 128 + wave * 16;
    int r = rowbase + (lane & 15);
    int kseg = lane >> 4;
    const float* xr = (r < N) ? (x + (size_t)r * INF) : emb;

    auto stage = [&](int kk, int buf) {
        #pragma unroll
        for (int q = 0; q < 2; ++q) {
            int idx = q * 512 + threadIdx.x;    // [0,1024) f4-units; 16B/lane stride
            int d = idx >> 9, r9 = idx & 511;
            const bf16_t* Wsrc = d ? WfBU : WfTD;
            *reinterpret_cast<float4*>(WS + (size_t)(buf * 8192 + idx * 8)) =
                *reinterpret_cast<const float4*>(Wsrc + ((size_t)(kk << 9) + r9) * 8);
        }
    };

    // A-fragments: all 16 float4 loads issued up front
    bf16x8 a[8];
    #pragma unroll
    for (int h = 0; h < 2; ++h) {
        float4 f[8];
        #pragma unroll
        for (int kk = 0; kk < 4; ++kk) {
            int k0 = (h * 4 + kk) * 32 + kseg * 8;
            f[2 * kk]     = *reinterpret_cast<const float4*>(xr + k0);
            f[2 * kk + 1] = *reinterpret_cast<const float4*>(xr + k0 + 4);
        }
        #pragma unroll
        for (int kk = 0; kk < 4; ++kk) {
            bf16x8 av;
            av[0] = (__bf16)f[2 * kk].x;     av[1] = (__bf16)f[2 * kk].y;
            av[2] = (__bf16)f[2 * kk].z;     av[3] = (__bf16)f[2 * kk].w;
            av[4] = (__bf16)f[2 * kk + 1].x; av[5] = (__bf16)f[2 * kk + 1].y;
            av[6] = (__bf16)f[2 * kk + 1].z; av[7] = (__bf16)f[2 * kk + 1].w;
            a[h * 4 + kk] = av;
        }
    }

    stage(0, 0);
    __syncthreads();

    f32x4 accT[8] = {}, accB[8] = {};
    #pragma unroll
    for (int kk = 0; kk < 8; ++kk) {
        int cur = kk & 1;
        if (kk < 7) stage(kk + 1, cur ^ 1);   // overlap next stage with MFMAs
        const bf16_t* wb = WS + cur * 8192;
        #pragma unroll
        for (int n = 0; n < 8; ++n) {
            bf16x8 bt = *reinterpret_cast<const bf16x8*>(wb + (size_t)(((n << 6) + lane)) * 8);
            accT[n] = __builtin_amdgcn_mfma_f32_16x16x32_bf16(a[kk], bt, accT[n], 0, 0, 0);
            bf16x8 bb = *reinterpret_cast<const bf16x8*>(wb + 4096 + (size_t)(((n << 6) + lane)) * 8);
            accB[n] = __builtin_amdgcn_mfma_f32_16x16x32_bf16(a[kk], bb, accB[n], 0, 0, 0);
        }
        if (kk < 7) __syncthreads();
    }

    int ccol = lane & 15;
    int cg = lane >> 4;
    #pragma unroll
    for (int i = 0; i < 4; ++i) {
        int rr = rowbase + cg * 4 + i;
        if (rr >= nv) continue;
        float diT = dinvTD[rr], diB = dinvBU[rr];
        bf16_t* oT = rawsTD + (size_t)rr * HF + ccol;
        bf16_t* oB = rawsBU + (size_t)rr * HF + ccol;
        #pragma unroll
        for (int n = 0; n < 8; ++n) {
            oT[n * 16] = (bf16_t)(accT[n][i] * diT);
            oB[n * 16] = (bf16_t)(accB[n][i] * diB);
        }
    }
}

// layer-1 gather, both dirs:
//   S[v] = dinv[v] * relu(dinv[v]*(raws[v] + sum_in raws[s]) + b1)   (bf16)
// float2-plane accumulation; slot loads software-pipelined one chunk ahead.
__global__ __launch_bounds__(128) void k_gather1(
    const bf16_t* __restrict__ raws, const int* __restrict__ off,
    const int* __restrict__ slots,
    const float* __restrict__ dinv,
    const float* __restrict__ td_b1, const float* __restrict__ bu_b1,
    bf16_t* __restrict__ ab, int nv, int EB)
{
    int dir = blockIdx.y;
    const bf16_t* R  = raws + (size_t)dir * nv * HF;
    const int*    OF = off + (size_t)dir * (nv + 1);
    const int*    SL = slots + (size_t)dir * EB;
    const float*  DV = dinv + (size_t)dir * nv;
    const float*  bias = dir ? bu_b1 : td_b1;
    bf16_t* AB = ab + (size_t)dir * nv * HF;

    __shared__ float2 buf[2][NPB][64];
    int t = threadIdx.x;
    int h = t >> 6;
    int c = t & 63;
    int v0 = blockIdx.x * NPB;

    // self rows of my parity (NH rows), 4B loads
    unsigned selfw[NH];
    #pragma unroll
    for (int jj = 0; jj < NH; ++jj) {
        int v = min(v0 + 2 * jj + h, nv - 1);
        selfw[jj] = *reinterpret_cast<const unsigned*>(R + (size_t)v * HF + 2 * c);
    }
    __builtin_amdgcn_sched_barrier(0);
    #pragma unroll
    for (int jj = 0; jj < NH; ++jj) {
        float2 f = bf2_to_f2(selfw[jj]);
        buf[h][2 * jj + h][c] = f;
        buf[h][2 * jj + (1 - h)][c] = make_float2(0.f, 0.f);
    }

    int e0 = OF[v0], e1 = OF[min(v0 + NPB, nv)];
    int w[CHP];
    if (e0 < e1) {
        #pragma unroll
        for (int u = 0; u < CHP; ++u) w[u] = SL[min(e0 + 2 * u + h, e1 - 1)];
    }
    #pragma unroll 1
    for (int i = e0; i < e1; i += 2 * CHP) {
        __builtin_amdgcn_sched_barrier(0);
        unsigned vw[CHP];
        #pragma unroll
        for (int u = 0; u < CHP; ++u)
            vw[u] = *reinterpret_cast<const unsigned*>(R + (size_t)(w[u] & SLMASK) * HF + 2 * c);
        int wn[CHP];
        int inx = i + 2 * CHP;
        if (inx < e1) {                     // prefetch next chunk's slot words
            #pragma unroll
            for (int u = 0; u < CHP; ++u) wn[u] = SL[min(inx + 2 * u + h, e1 - 1)];
        }
        __builtin_amdgcn_sched_barrier(0);
        #pragma unroll
        for (int u = 0; u < CHP; ++u) {
            if (i + 2 * u + h < e1) {
                float2 f = bf2_to_f2(vw[u]);
                int j = w[u] >> 24;
                float2 cur = buf[h][j][c];
                buf[h][j][c] = make_float2(cur.x + f.x, cur.y + f.y);
            }
        }
        #pragma unroll
        for (int u = 0; u < CHP; ++u) w[u] = wn[u];
    }
    __syncthreads();

    float bs0 = bias[2 * c], bs1 = bias[2 * c + 1];
    #pragma unroll 1
    for (int jj = 0; jj < NH; ++jj) {
        int j = 2 * jj + h;
        int v = v0 + j;
        if (v >= nv) break;
        float2 a0 = buf[0][j][c], a1 = buf[1][j][c];
        float dv = DV[v];
        float x0 = dv * (a0.x + a1.x) + bs0;
        float x1 = dv * (a0.y + a1.y) + bs1;
        unsigned o = f2_to_bf2(dv * fmaxf(x0, 0.f), dv * fmaxf(x1, 0.f));
        *reinterpret_cast<unsigned*>(AB + (size_t)v * HF + 2 * c) = o;
    }
}

// layer-2 gather + pool, both dirs:
//   G[v] = dinv[v]*(S[v] + sum_in S[s]);  pooled[g] += G[v] (run-length); vrow = G[N]
__global__ __launch_bounds__(128) void k_gather2pool(
    const bf16_t* __restrict__ ab, const int* __restrict__ off,
    const int* __restrict__ slots,
    const float* __restrict__ dinv, const int* __restrict__ batch,
    float* __restrict__ pooled, float* __restrict__ vrow,
    int nv, int EB, int N, int B)
{
    int dir = blockIdx.y;
    const bf16_t* S  = ab + (size_t)dir * nv * HF;
    const int*    OF = off + (size_t)dir * (nv + 1);
    const int*    SL = slots + (size_t)dir * EB;
    const float*  DV = dinv + (size_t)dir * nv;
    float* PP = pooled + (size_t)dir * B * HF;
    float* VR = vrow + dir * HF;

    __shared__ float2 buf[2][NPB][64];
    int t = threadIdx.x;
    int h = t >> 6;
    int c = t & 63;
    int v0 = blockIdx.x * NPB;

    unsigned selfw[NH];
    #pragma unroll
    for (int jj = 0; jj < NH; ++jj) {
        int v = min(v0 + 2 * jj + h, nv - 1);
        selfw[jj] = *reinterpret_cast<const unsigned*>(S + (size_t)v * HF + 2 * c);
    }
    __builtin_amdgcn_sched_barrier(0);
    #pragma unroll
    for (int jj = 0; jj < NH; ++jj) {
        float2 f = bf2_to_f2(selfw[jj]);
        buf[h][2 * jj + h][c] = f;
        buf[h][2 * jj + (1 - h)][c] = make_float2(0.f, 0.f);
    }

    int e0 = OF[v0], e1 = OF[min(v0 + NPB, nv)];
    int w[CHP];
    if (e0 < e1) {
        #pragma unroll
        for (int u = 0; u < CHP; ++u) w[u] = SL[min(e0 + 2 * u + h, e1 - 1)];
    }
    #pragma unroll 1
    for (int i = e0; i < e1; i += 2 * CHP) {
        __builtin_amdgcn_sched_barrier(0);
        unsigned vw[CHP];
        #pragma unroll
        for (int u = 0; u < CHP; ++u)
            vw[u] = *reinterpret_cast<const unsigned*>(S + (size_t)(w[u] & SLMASK) * HF + 2 * c);
        int wn[CHP];
        int inx = i + 2 * CHP;
        if (inx < e1) {
            #pragma unroll
            for (int u = 0; u < CHP; ++u) wn[u] = SL[min(inx + 2 * u + h, e1 - 1)];
        }
        __builtin_amdgcn_sched_barrier(0);
        #pragma unroll
        for (int u = 0; u < CHP; ++u) {
            if (i + 2 * u + h < e1) {
                float2 f = bf2_to_f2(vw[u]);
                int j = w[u] >> 24;
                float2 cur = buf[h][j][c];
                buf[h][j][c] = make_float2(cur.x + f.x, cur.y + f.y);
            }
        }
        #pragma unroll
        for (int u = 0; u < CHP; ++u) w[u] = wn[u];
    }
    __syncthreads();

    // run-length pooling over my-parity rows (batch sorted); vrow direct store
    float acc0 = 0.f, acc1 = 0.f;
    int curg = -1;
    #pragma unroll 1
    for (int jj = 0; jj < NH; ++jj) {
        int j = 2 * jj + h;
        int v = v0 + j;
        if (v >= nv) break;
        float2 a0 = buf[0][j][c], a1 = buf[1][j][c];
        float dv = DV[v];
        float G0 = dv * (a0.x + a1.x);
        float G1 = dv * (a0.y + a1.y);
        if (v == N) { VR[2 * c] = G0; VR[2 * c + 1] = G1; continue; }
        int g = batch[v];
        if (g != curg) {
            if (curg >= 0) {
                atomicAdd(&PP[curg * HF + 2 * c], acc0);
                atomicAdd(&PP[curg * HF + 2 * c + 1], acc1);
            }
            curg = g; acc0 = 0.f; acc1 = 0.f;
        }
        acc0 += G0; acc1 += G1;
    }
    if (curg >= 0) {
        atomicAdd(&PP[curg * HF + 2 * c], acc0);
        atomicAdd(&PP[curg * HF + 2 * c + 1], acc1);
    }
}

// Per graph: z = pooled_pre + vrow_pre; u = z @ W2 + (cnt+1)*b2 per branch;
// out = relu([u_bu, u_td] @ w1 + b1) @ w2 + b2
__global__ __launch_bounds__(256) void k_mlp(
    const float* __restrict__ pooled, const float* __restrict__ vrow, const int* __restrict__ roots,
    const float* __restrict__ td_w2, const float* __restrict__ td_b2,
    const float* __restrict__ bu_w2, const float* __restrict__ bu_b2,
    const float* __restrict__ w1, const float* __restrict__ b1,
    const float* __restrict__ w2, const float* __restrict__ b2,
    float* __restrict__ out, int B)
{
    __shared__ float zsh[256];
    __shared__ float invec[256];
    __shared__ float hid[256];
    int g = blockIdx.x;
    int t = threadIdx.x;
    const float* pp_td = pooled;
    const float* pp_bu = pooled + (size_t)B * HF;
    const float* vr_td = vrow;
    const float* vr_bu = vrow + HF;
    zsh[t] = (t < 128) ? (pp_bu[g * HF + t] + vr_bu[t])
                       : (pp_td[g * HF + (t - 128)] + vr_td[t - 128]);
    __syncthreads();
    float cnt1 = (float)(roots[g + 1] - roots[g] + 1);
    float acc2;
    if (t < 128) {
        acc2 = cnt1 * bu_b2[t];
        #pragma unroll 8
        for (int k = 0; k < 128; ++k) acc2 = fmaf(zsh[k], bu_w2[k * HF + t], acc2);
    } else {
        int tt = t - 128;
        acc2 = cnt1 * td_b2[tt];
        #pragma unroll 8
        for (int k = 0; k < 128; ++k) acc2 = fmaf(zsh[128 + k], td_w2[k * HF + tt], acc2);
    }
    invec[t] = acc2;
    __syncthreads();
    float acc = b1[t];
    #pragma unroll 8
    for (int k = 0; k < 256; ++k) acc = fmaf(invec[k], w1[k * 256 + t], acc);
    hid[t] = acc > 0.f ? acc : 0.f;
    __syncthreads();
    if (t < 128) {
        float o = b2[t];
        #pragma unroll 8
        for (int k = 0; k < 256; ++k) o = fmaf(hid[k], w2[k * 128 + t], o);
        out[g * 128 + t] = o;
    }
}

extern "C" void kernel_launch(void* const* d_in, const int* in_sizes, int n_in,
                              void* d_out, int out_size, void* d_ws, size_t ws_size,
                              hipStream_t stream) {
    const float* x     = (const float*)d_in[0];
    const float* emb_w = (const float*)d_in[1];
    const float* td_w1 = (const float*)d_in[2];
    const float* td_b1 = (const float*)d_in[3];
    const float* td_w2 = (const float*)d_in[4];
    const float* td_b2 = (const float*)d_in[5];
    const float* bu_w1 = (const float*)d_in[6];
    const float* bu_b1 = (const float*)d_in[7];
    const float* bu_w2 = (const float*)d_in[8];
    const float* bu_b2 = (const float*)d_in[9];
    const float* p_w1  = (const float*)d_in[10];
    const float* p_b1  = (const float*)d_in[11];
    const float* p_w2  = (const float*)d_in[12];
    const float* p_b2  = (const float*)d_in[13];
    const int*   ei    = (const int*)d_in[14];
    const int*   batch = (const int*)d_in[15];

    int N = in_sizes[0] / INF;
    int E = in_sizes[14] / 2;
    int B = out_size / 128;
    int nv = N + 1;
    int EB = E + B;
    const int* src = ei;
    const int* dst = ei + E;

    // ---- workspace carve-up ----
    char* wsp = (char*)d_ws;
    auto alloc = [&](size_t bytes) { char* p = wsp; wsp += (bytes + 255) & ~(size_t)255; return p; };
    // zero region: [indeg 2*nv][pooled 2*B*HF][vrow 2*HF]
    int zwords = 2 * nv + 2 * B * HF + 2 * HF;
    int*    Z      = (int*)   alloc((size_t)zwords * 4);
    int*    indeg  = Z;
    float*  pooled = (float*)(Z + 2 * nv);
    float*  vrow   = pooled + 2 * B * HF;
    float*  dinv   = (float*) alloc((size_t)2 * nv * 4);
    int*    off    = (int*)   alloc((size_t)2 * (nv + 1) * 4);
    int*    cursor = (int*)   alloc((size_t)2 * nv * 4);
    int*    slots  = (int*)   alloc((size_t)2 * EB * 4);
    int*    bsum   = (int*)   alloc((size_t)2 * SCAN_STRIDE * 4);
    int*    roots  = (int*)   alloc((size_t)(B + 1) * 4);
    bf16_t* Wf     = (bf16_t*)alloc((size_t)65536 * 2);
    bf16_t* RAWS   = (bf16_t*)alloc((size_t)2 * nv * HF * 2);  // dir-major
    bf16_t* AB     = (bf16_t*)alloc((size_t)2 * nv * HF * 2);  // dir-major

    float* out = (float*)d_out;

    dim3 b256(256), b128(128);
    int nblk = (nv + 255) / 256;
    int ngb = (nv + NPB - 1) / NPB;
    int nvb = (nv + 127) / 128;
    int imax = max(zwords, N);

    k_init<<<dim3((imax + 255) / 256), b256, 0, stream>>>(batch, roots, Z, N, B, zwords);
    k_wswz2<<<dim3((65536 + 255) / 256), b256, 0, stream>>>(td_w1, bu_w1, Wf);
    k_degboth<<<dim3((EB + 255) / 256), b256, 0, stream>>>(src, dst, roots, indeg, E, B, N, nv);
    k_dinvboth<<<dim3((2 * nv + 255) / 256), b256, 0, stream>>>(indeg, dinv, 2 * nv);
    k_scan1<<<dim3(nblk, 2), b256, 0, stream>>>(indeg, bsum, nv);
    k_scan2<<<dim3(1, 2), dim3(512), 0, stream>>>(bsum, nblk);
    k_scan3<<<dim3(nblk, 2), b256, 0, stream>>>(indeg, bsum, off, cursor, nv, EB);
    k_fill<<<dim3((EB + 255) / 256), b256, 0, stream>>>(src, dst, roots, cursor, slots, E, B, N, nv);

    k_gemm1both<<<dim3(nvb), dim3(512), 0, stream>>>(
        x, emb_w, Wf, Wf + 32768, dinv, dinv + nv,
        RAWS, RAWS + (size_t)nv * HF, nv, N);

    k_gather1<<<dim3(ngb, 2), b128, 0, stream>>>(
        RAWS, off, slots, dinv, td_b1, bu_b1, AB, nv, EB);

    k_gather2pool<<<dim3(ngb, 2), b128, 0, stream>>>(
        AB, off, slots, dinv, batch, pooled, vrow, nv, EB, N, B);

    k_mlp<<<dim3(B), b256, 0, stream>>>(
        pooled, vrow, roots, td_w2, td_b2, bu_w2, bu_b2,
        p_w1, p_b1, p_w2, p_b2, out, B);
}

// Round 19
// 208.282 us; speedup vs baseline: 1.1387x; 1.1387x over previous
//
#include <hip/hip_runtime.h>

typedef __bf16 bf16_t;
typedef __bf16 bf16x8 __attribute__((ext_vector_type(8)));
typedef float f32x4 __attribute__((ext_vector_type(4)));

#define INF 256
#define HF 128
#define NPB 16
#define CHP 16          // edges per parity-plane per chunk (32 total)
#define SLMASK 0x00FFFFFF
#define SCAN_STRIDE 512

__device__ inline float2 bf2_to_f2(unsigned v) {
    float lo = __uint_as_float(v << 16);
    float hi = __uint_as_float(v & 0xffff0000u);
    return make_float2(lo, hi);
}
__device__ inline unsigned f2_to_bf2(float a, float b) {
    __bf16 x = (__bf16)a, y = (__bf16)b;
    unsigned short ux = __builtin_bit_cast(unsigned short, x);
    unsigned short uy = __builtin_bit_cast(unsigned short, y);
    return (unsigned)ux | ((unsigned)uy << 16);
}

// ---- merged init: zero region + roots[g] + W-swizzle (independent ranges) ----
__global__ void k_init(const int* __restrict__ batch, int* __restrict__ roots,
                       int* __restrict__ Z, int N, int B, int zwords,
                       const float* __restrict__ tw1, const float* __restrict__ bw1,
                       bf16_t* __restrict__ o) {
    int i = blockIdx.x * blockDim.x + threadIdx.x;
    if (i < zwords) Z[i] = 0;
    if (i == 0) roots[B] = N;
    if (i < N) {
        if (i == 0) roots[batch[0]] = 0;
        else if (batch[i] != batch[i - 1]) roots[batch[i]] = i;
    }
    if (i < 65536) {   // W swizzle: two 256x128 f32 -> bf16 MFMA B-fragment order
        const float* W = (i < 32768) ? tw1 : bw1;
        bf16_t* out = o + (i & 32768);
        int ii = i & 32767;
        int j  = ii & 7;
        int l  = (ii >> 3) & 63;
        int t  = ii >> 9;          // kk*8 + n
        int n  = t & 7;
        int kk = t >> 3;
        int k  = kk * 32 + ((l >> 4) << 3) + j;
        int c  = (n << 4) + (l & 15);
        out[ii] = (bf16_t)W[k * HF + c];
    }
}

// in-degree for both directions. TD: d=dst. BU: d=src. Virtual edge N->root.
__global__ void k_degboth(const int* __restrict__ src, const int* __restrict__ dst,
                          const int* __restrict__ roots, int* __restrict__ indeg,
                          int E, int B, int N, int nv) {
    int e = blockIdx.x * blockDim.x + threadIdx.x;
    if (e >= E + B) return;
    int a, b;
    if (e < E) { a = src[e]; b = dst[e]; }
    else       { a = N;      b = roots[e - E]; }
    atomicAdd(&indeg[b], 1);        // TD
    atomicAdd(&indeg[nv + a], 1);   // BU
}

// per-256-chunk sums
__global__ __launch_bounds__(256) void k_scan1(const int* __restrict__ indeg, int* __restrict__ bsum, int nv) {
    int dir = blockIdx.y;
    __shared__ int s[256];
    int t = threadIdx.x;
    int v = blockIdx.x * 256 + t;
    s[t] = (v < nv) ? indeg[dir * nv + v] : 0;
    __syncthreads();
    for (int off = 128; off > 0; off >>= 1) {
        if (t < off) s[t] += s[t + off];
        __syncthreads();
    }
    if (t == 0) bsum[dir * SCAN_STRIDE + blockIdx.x] = s[0];
}

// exclusive scan of block sums (nblk <= 512)
__global__ __launch_bounds__(512) void k_scan2(int* __restrict__ bsum, int nblk) {
    int dir = blockIdx.y;
    int* p = bsum + dir * SCAN_STRIDE;
    __shared__ int s[512];
    int t = threadIdx.x;
    int v = (t < nblk) ? p[t] : 0;
    s[t] = v;
    __syncthreads();
    for (int off = 1; off < 512; off <<= 1) {
        int u = (t >= off) ? s[t - off] : 0;
        __syncthreads();
        s[t] += u;
        __syncthreads();
    }
    if (t < nblk) p[t] = s[t] - v;  // exclusive
}

// per-element exclusive offsets + cursor copy + dinv (fused)
__global__ __launch_bounds__(256) void k_scan3(const int* __restrict__ indeg, const int* __restrict__ bsum,
                                               int* __restrict__ off, int* __restrict__ cursor,
                                               float* __restrict__ dinv,
                                               int nv, int total) {
    int dir = blockIdx.y;
    __shared__ int s[256];
    int t = threadIdx.x;
    int v0 = blockIdx.x * 256 + t;
    int val = (v0 < nv) ? indeg[dir * nv + v0] : 0;
    s[t] = val;
    __syncthreads();
    for (int o = 1; o < 256; o <<= 1) {
        int u = (t >= o) ? s[t - o] : 0;
        __syncthreads();
        s[t] += u;
        __syncthreads();
    }
    int excl = s[t] - val + bsum[dir * SCAN_STRIDE + blockIdx.x];
    if (v0 < nv) {
        off[dir * (nv + 1) + v0] = excl;
        cursor[dir * nv + v0] = excl;
        dinv[dir * nv + v0] = rsqrtf(1.0f + (float)val);   // +1 self-loop
    }
    if (blockIdx.x == 0 && t == 0) off[dir * (nv + 1) + nv] = total;
}

// fill packed slot lists for both directions: word = src | ((owner & 15) << 24)
__global__ void k_fill(const int* __restrict__ src, const int* __restrict__ dst,
                       const int* __restrict__ roots, int* __restrict__ cursor,
                       int* __restrict__ slots,
                       int E, int B, int N, int nv) {
    int e = blockIdx.x * blockDim.x + threadIdx.x;
    if (e >= E + B) return;
    int EB = E + B;
    int a, b;
    if (e < E) { a = src[e]; b = dst[e]; }
    else       { a = N;      b = roots[e - E]; }
    int p = atomicAdd(&cursor[b], 1);            // TD: owner b, source a
    slots[p] = a | ((b & (NPB - 1)) << 24);
    p = atomicAdd(&cursor[nv + a], 1);           // BU: owner a, source b
    slots[EB + p] = b | ((a & (NPB - 1)) << 24);
}

// Dual-direction MFMA GEMM1: 128 rows/block (8 waves). W staged per-kk into a
// DOUBLE-buffered 32KB LDS slab (conflict-free 16B/lane stride).
__global__ __launch_bounds__(512) void k_gemm1both(
    const float* __restrict__ x, const float* __restrict__ emb,
    const bf16_t* __restrict__ WfTD, const bf16_t* __restrict__ WfBU,
    const float* __restrict__ dinvTD, const float* __restrict__ dinvBU,
    bf16_t* __restrict__ rawsTD, bf16_t* __restrict__ rawsBU,
    int nv, int N)
{
    __shared__ bf16_t WS[2 * 8192];   // 2 x 16 KB; f4-unit idx: d*512 + n*64 + lane
    int lane = threadIdx.x & 63;
    int wave = threadIdx.x >> 6;        // 0..7
    int rowbase = blockIdx.x * 128 + wave * 16;
    int r = rowbase + (lane & 15);
    int kseg = lane >> 4;
    const float* xr = (r < N) ? (x + (size_t)r * INF) : emb;

    auto stage = [&](int kk, int buf) {
        #pragma unroll
        for (int q = 0; q < 2; ++q) {
            int idx = q * 512 + threadIdx.x;    // [0,1024) f4-units; 16B/lane stride
            int d = idx >> 9, r9 = idx & 511;
            const bf16_t* Wsrc = d ? WfBU : WfTD;
            *reinterpret_cast<float4*>(WS + (size_t)(buf * 8192 + idx * 8)) =
                *reinterpret_cast<const float4*>(Wsrc + ((size_t)(kk << 9) + r9) * 8);
        }
    };

    // A-fragments: all 16 float4 loads issued up front
    bf16x8 a[8];
    #pragma unroll
    for (int h = 0; h < 2; ++h) {
        float4 f[8];
        #pragma unroll
        for (int kk = 0; kk < 4; ++kk) {
            int k0 = (h * 4 + kk) * 32 + kseg * 8;
            f[2 * kk]     = *reinterpret_cast<const float4*>(xr + k0);
            f[2 * kk + 1] = *reinterpret_cast<const float4*>(xr + k0 + 4);
        }
        #pragma unroll
        for (int kk = 0; kk < 4; ++kk) {
            bf16x8 av;
            av[0] = (__bf16)f[2 * kk].x;     av[1] = (__bf16)f[2 * kk].y;
            av[2] = (__bf16)f[2 * kk].z;     av[3] = (__bf16)f[2 * kk].w;
            av[4] = (__bf16)f[2 * kk + 1].x; av[5] = (__bf16)f[2 * kk + 1].y;
            av[6] = (__bf16)f[2 * kk + 1].z; av[7] = (__bf16)f[2 * kk + 1].w;
            a[h * 4 + kk] = av;
        }
    }

    stage(0, 0);
    __syncthreads();

    f32x4 accT[8] = {}, accB[8] = {};
    #pragma unroll
    for (int kk = 0; kk < 8; ++kk) {
        int cur = kk & 1;
        if (kk < 7) stage(kk + 1, cur ^ 1);   // overlap next stage with MFMAs
        const bf16_t* wb = WS + cur * 8192;
        #pragma unroll
        for (int n = 0; n < 8; ++n) {
            bf16x8 bt = *reinterpret_cast<const bf16x8*>(wb + (size_t)(((n << 6) + lane)) * 8);
            accT[n] = __builtin_amdgcn_mfma_f32_16x16x32_bf16(a[kk], bt, accT[n], 0, 0, 0);
            bf16x8 bb = *reinterpret_cast<const bf16x8*>(wb + 4096 + (size_t)(((n << 6) + lane)) * 8);
            accB[n] = __builtin_amdgcn_mfma_f32_16x16x32_bf16(a[kk], bb, accB[n], 0, 0, 0);
        }
        if (kk < 7) __syncthreads();
    }

    int ccol = lane & 15;
    int cg = lane >> 4;
    #pragma unroll
    for (int i = 0; i < 4; ++i) {
        int rr = rowbase + cg * 4 + i;
        if (rr >= nv) continue;
        float diT = dinvTD[rr], diB = dinvBU[rr];
        bf16_t* oT = rawsTD + (size_t)rr * HF + ccol;
        bf16_t* oB = rawsBU + (size_t)rr * HF + ccol;
        #pragma unroll
        for (int n = 0; n < 8; ++n) {
            oT[n * 16] = (bf16_t)(accT[n][i] * diT);
            oB[n * 16] = (bf16_t)(accB[n][i] * diB);
        }
    }
}

// layer-1 gather, both dirs:
//   S[v] = dinv[v] * relu(dinv[v]*(raws[v] + sum_in raws[s]) + b1)   (bf16)
// float2-plane accumulation; slot loads software-pipelined one chunk ahead.
__global__ __launch_bounds__(128) void k_gather1(
    const bf16_t* __restrict__ raws, const int* __restrict__ off,
    const int* __restrict__ slots,
    const float* __restrict__ dinv,
    const float* __restrict__ td_b1, const float* __restrict__ bu_b1,
    bf16_t* __restrict__ ab, int nv, int EB)
{
    int dir = blockIdx.y;
    const bf16_t* R  = raws + (size_t)dir * nv * HF;
    const int*    OF = off + (size_t)dir * (nv + 1);
    const int*    SL = slots + (size_t)dir * EB;
    const float*  DV = dinv + (size_t)dir * nv;
    const float*  bias = dir ? bu_b1 : td_b1;
    bf16_t* AB = ab + (size_t)dir * nv * HF;

    __shared__ float2 buf[2][NPB][64];
    int t = threadIdx.x;
    int h = t >> 6;
    int c = t & 63;
    int v0 = blockIdx.x * NPB;

    // self rows of my parity (8 rows), 4B loads
    unsigned selfw[8];
    #pragma unroll
    for (int jj = 0; jj < 8; ++jj) {
        int v = min(v0 + 2 * jj + h, nv - 1);
        selfw[jj] = *reinterpret_cast<const unsigned*>(R + (size_t)v * HF + 2 * c);
    }
    __builtin_amdgcn_sched_barrier(0);
    #pragma unroll
    for (int jj = 0; jj < 8; ++jj) {
        float2 f = bf2_to_f2(selfw[jj]);
        buf[h][2 * jj + h][c] = f;
        buf[h][2 * jj + (1 - h)][c] = make_float2(0.f, 0.f);
    }

    int e0 = OF[v0], e1 = OF[min(v0 + NPB, nv)];
    int w[CHP];
    if (e0 < e1) {
        #pragma unroll
        for (int u = 0; u < CHP; ++u) w[u] = SL[min(e0 + 2 * u + h, e1 - 1)];
    }
    #pragma unroll 1
    for (int i = e0; i < e1; i += 2 * CHP) {
        __builtin_amdgcn_sched_barrier(0);
        unsigned vw[CHP];
        #pragma unroll
        for (int u = 0; u < CHP; ++u)
            vw[u] = *reinterpret_cast<const unsigned*>(R + (size_t)(w[u] & SLMASK) * HF + 2 * c);
        int wn[CHP];
        int inx = i + 2 * CHP;
        if (inx < e1) {                     // prefetch next chunk's slot words
            #pragma unroll
            for (int u = 0; u < CHP; ++u) wn[u] = SL[min(inx + 2 * u + h, e1 - 1)];
        }
        __builtin_amdgcn_sched_barrier(0);
        #pragma unroll
        for (int u = 0; u < CHP; ++u) {
            if (i + 2 * u + h < e1) {
                float2 f = bf2_to_f2(vw[u]);
                int j = w[u] >> 24;
                float2 cur = buf[h][j][c];
                buf[h][j][c] = make_float2(cur.x + f.x, cur.y + f.y);
            }
        }
        #pragma unroll
        for (int u = 0; u < CHP; ++u) w[u] = wn[u];
    }
    __syncthreads();

    float bs0 = bias[2 * c], bs1 = bias[2 * c + 1];
    #pragma unroll 1
    for (int jj = 0; jj < 8; ++jj) {
        int j = 2 * jj + h;
        int v = v0 + j;
        if (v >= nv) break;
        float2 a0 = buf[0][j][c], a1 = buf[1][j][c];
        float dv = DV[v];
        float x0 = dv * (a0.x + a1.x) + bs0;
        float x1 = dv * (a0.y + a1.y) + bs1;
        unsigned o = f2_to_bf2(dv * fmaxf(x0, 0.f), dv * fmaxf(x1, 0.f));
        *reinterpret_cast<unsigned*>(AB + (size_t)v * HF + 2 * c) = o;
    }
}

// layer-2 gather + pool, both dirs:
//   G[v] = dinv[v]*(S[v] + sum_in S[s]);  pooled[g] += G[v] (run-length); vrow = G[N]
__global__ __launch_bounds__(128) void k_gather2pool(
    const bf16_t* __restrict__ ab, const int* __restrict__ off,
    const int* __restrict__ slots,
    const float* __restrict__ dinv, const int* __restrict__ batch,
    float* __restrict__ pooled, float* __restrict__ vrow,
    int nv, int EB, int N, int B)
{
    int dir = blockIdx.y;
    const bf16_t* S  = ab + (size_t)dir * nv * HF;
    const int*    OF = off + (size_t)dir * (nv + 1);
    const int*    SL = slots + (size_t)dir * EB;
    const float*  DV = dinv + (size_t)dir * nv;
    float* PP = pooled + (size_t)dir * B * HF;
    float* VR = vrow + dir * HF;

    __shared__ float2 buf[2][NPB][64];
    int t = threadIdx.x;
    int h = t >> 6;
    int c = t & 63;
    int v0 = blockIdx.x * NPB;

    unsigned selfw[8];
    #pragma unroll
    for (int jj = 0; jj < 8; ++jj) {
        int v = min(v0 + 2 * jj + h, nv - 1);
        selfw[jj] = *reinterpret_cast<const unsigned*>(S + (size_t)v * HF + 2 * c);
    }
    __builtin_amdgcn_sched_barrier(0);
    #pragma unroll
    for (int jj = 0; jj < 8; ++jj) {
        float2 f = bf2_to_f2(selfw[jj]);
        buf[h][2 * jj + h][c] = f;
        buf[h][2 * jj + (1 - h)][c] = make_float2(0.f, 0.f);
    }

    int e0 = OF[v0], e1 = OF[min(v0 + NPB, nv)];
    int w[CHP];
    if (e0 < e1) {
        #pragma unroll
        for (int u = 0; u < CHP; ++u) w[u] = SL[min(e0 + 2 * u + h, e1 - 1)];
    }
    #pragma unroll 1
    for (int i = e0; i < e1; i += 2 * CHP) {
        __builtin_amdgcn_sched_barrier(0);
        unsigned vw[CHP];
        #pragma unroll
        for (int u = 0; u < CHP; ++u)
            vw[u] = *reinterpret_cast<const unsigned*>(S + (size_t)(w[u] & SLMASK) * HF + 2 * c);
        int wn[CHP];
        int inx = i + 2 * CHP;
        if (inx < e1) {
            #pragma unroll
            for (int u = 0; u < CHP; ++u) wn[u] = SL[min(inx + 2 * u + h, e1 - 1)];
        }
        __builtin_amdgcn_sched_barrier(0);
        #pragma unroll
        for (int u = 0; u < CHP; ++u) {
            if (i + 2 * u + h < e1) {
                float2 f = bf2_to_f2(vw[u]);
                int j = w[u] >> 24;
                float2 cur = buf[h][j][c];
                buf[h][j][c] = make_float2(cur.x + f.x, cur.y + f.y);
            }
        }
        #pragma unroll
        for (int u = 0; u < CHP; ++u) w[u] = wn[u];
    }
    __syncthreads();

    // run-length pooling over my-parity rows (batch sorted); vrow direct store
    float acc0 = 0.f, acc1 = 0.f;
    int curg = -1;
    #pragma unroll 1
    for (int jj = 0; jj < 8; ++jj) {
        int j = 2 * jj + h;
        int v = v0 + j;
        if (v >= nv) break;
        float2 a0 = buf[0][j][c], a1 = buf[1][j][c];
        float dv = DV[v];
        float G0 = dv * (a0.x + a1.x);
        float G1 = dv * (a0.y + a1.y);
        if (v == N) { VR[2 * c] = G0; VR[2 * c + 1] = G1; continue; }
        int g = batch[v];
        if (g != curg) {
            if (curg >= 0) {
                atomicAdd(&PP[curg * HF + 2 * c], acc0);
                atomicAdd(&PP[curg * HF + 2 * c + 1], acc1);
            }
            curg = g; acc0 = 0.f; acc1 = 0.f;
        }
        acc0 += G0; acc1 += G1;
    }
    if (curg >= 0) {
        atomicAdd(&PP[curg * HF + 2 * c], acc0);
        atomicAdd(&PP[curg * HF + 2 * c + 1], acc1);
    }
}

// Per graph: z = pooled_pre + vrow_pre; u = z @ W2 + (cnt+1)*b2 per branch;
// out = relu([u_bu, u_td] @ w1 + b1) @ w2 + b2
__global__ __launch_bounds__(256) void k_mlp(
    const float* __restrict__ pooled, const float* __restrict__ vrow, const int* __restrict__ roots,
    const float* __restrict__ td_w2, const float* __restrict__ td_b2,
    const float* __restrict__ bu_w2, const float* __restrict__ bu_b2,
    const float* __restrict__ w1, const float* __restrict__ b1,
    const float* __restrict__ w2, const float* __restrict__ b2,
    float* __restrict__ out, int B)
{
    __shared__ float zsh[256];
    __shared__ float invec[256];
    __shared__ float hid[256];
    int g = blockIdx.x;
    int t = threadIdx.x;
    const float* pp_td = pooled;
    const float* pp_bu = pooled + (size_t)B * HF;
    const float* vr_td = vrow;
    const float* vr_bu = vrow + HF;
    zsh[t] = (t < 128) ? (pp_bu[g * HF + t] + vr_bu[t])
                       : (pp_td[g * HF + (t - 128)] + vr_td[t - 128]);
    __syncthreads();
    float cnt1 = (float)(roots[g + 1] - roots[g] + 1);
    float acc2;
    if (t < 128) {
        acc2 = cnt1 * bu_b2[t];
        #pragma unroll 8
        for (int k = 0; k < 128; ++k) acc2 = fmaf(zsh[k], bu_w2[k * HF + t], acc2);
    } else {
        int tt = t - 128;
        acc2 = cnt1 * td_b2[tt];
        #pragma unroll 8
        for (int k = 0; k < 128; ++k) acc2 = fmaf(zsh[128 + k], td_w2[k * HF + tt], acc2);
    }
    invec[t] = acc2;
    __syncthreads();
    float acc = b1[t];
    #pragma unroll 8
    for (int k = 0; k < 256; ++k) acc = fmaf(invec[k], w1[k * 256 + t], acc);
    hid[t] = acc > 0.f ? acc : 0.f;
    __syncthreads();
    if (t < 128) {
        float o = b2[t];
        #pragma unroll 8
        for (int k = 0; k < 256; ++k) o = fmaf(hid[k], w2[k * 128 + t], o);
        out[g * 128 + t] = o;
    }
}

extern "C" void kernel_launch(void* const* d_in, const int* in_sizes, int n_in,
                              void* d_out, int out_size, void* d_ws, size_t ws_size,
                              hipStream_t stream) {
    const float* x     = (const float*)d_in[0];
    const float* emb_w = (const float*)d_in[1];
    const float* td_w1 = (const float*)d_in[2];
    const float* td_b1 = (const float*)d_in[3];
    const float* td_w2 = (const float*)d_in[4];
    const float* td_b2 = (const float*)d_in[5];
    const float* bu_w1 = (const float*)d_in[6];
    const float* bu_b1 = (const float*)d_in[7];
    const float* bu_w2 = (const float*)d_in[8];
    const float* bu_b2 = (const float*)d_in[9];
    const float* p_w1  = (const float*)d_in[10];
    const float* p_b1  = (const float*)d_in[11];
    const float* p_w2  = (const float*)d_in[12];
    const float* p_b2  = (const float*)d_in[13];
    const int*   ei    = (const int*)d_in[14];
    const int*   batch = (const int*)d_in[15];

    int N = in_sizes[0] / INF;
    int E = in_sizes[14] / 2;
    int B = out_size / 128;
    int nv = N + 1;
    int EB = E + B;
    const int* src = ei;
    const int* dst = ei + E;

    // ---- workspace carve-up ----
    char* wsp = (char*)d_ws;
    auto alloc = [&](size_t bytes) { char* p = wsp; wsp += (bytes + 255) & ~(size_t)255; return p; };
    // zero region: [indeg 2*nv][pooled 2*B*HF][vrow 2*HF]
    int zwords = 2 * nv + 2 * B * HF + 2 * HF;
    int*    Z      = (int*)   alloc((size_t)zwords * 4);
    int*    indeg  = Z;
    float*  pooled = (float*)(Z + 2 * nv);
    float*  vrow   = pooled + 2 * B * HF;
    float*  dinv   = (float*) alloc((size_t)2 * nv * 4);
    int*    off    = (int*)   alloc((size_t)2 * (nv + 1) * 4);
    int*    cursor = (int*)   alloc((size_t)2 * nv * 4);
    int*    slots  = (int*)   alloc((size_t)2 * EB * 4);
    int*    bsum   = (int*)   alloc((size_t)2 * SCAN_STRIDE * 4);
    int*    roots  = (int*)   alloc((size_t)(B + 1) * 4);
    bf16_t* Wf     = (bf16_t*)alloc((size_t)65536 * 2);
    bf16_t* RAWS   = (bf16_t*)alloc((size_t)2 * nv * HF * 2);  // dir-major
    bf16_t* AB     = (bf16_t*)alloc((size_t)2 * nv * HF * 2);  // dir-major

    float* out = (float*)d_out;

    dim3 b256(256), b128(128);
    int nblk = (nv + 255) / 256;
    int ngb = (nv + NPB - 1) / NPB;
    int nvb = (nv + 127) / 128;
    int imax = max(zwords, max(N, 65536));

    k_init<<<dim3((imax + 255) / 256), b256, 0, stream>>>(batch, roots, Z, N, B, zwords,
                                                          td_w1, bu_w1, Wf);
    k_degboth<<<dim3((EB + 255) / 256), b256, 0, stream>>>(src, dst, roots, indeg, E, B, N, nv);
    k_scan1<<<dim3(nblk, 2), b256, 0, stream>>>(indeg, bsum, nv);
    k_scan2<<<dim3(1, 2), dim3(512), 0, stream>>>(bsum, nblk);
    k_scan3<<<dim3(nblk, 2), b256, 0, stream>>>(indeg, bsum, off, cursor, dinv, nv, EB);
    k_fill<<<dim3((EB + 255) / 256), b256, 0, stream>>>(src, dst, roots, cursor, slots, E, B, N, nv);

    k_gemm1both<<<dim3(nvb), dim3(512), 0, stream>>>(
        x, emb_w, Wf, Wf + 32768, dinv, dinv + nv,
        RAWS, RAWS + (size_t)nv * HF, nv, N);

    k_gather1<<<dim3(ngb, 2), b128, 0, stream>>>(
        RAWS, off, slots, dinv, td_b1, bu_b1, AB, nv, EB);

    k_gather2pool<<<dim3(ngb, 2), b128, 0, stream>>>(
        AB, off, slots, dinv, batch, pooled, vrow, nv, EB, N, B);

    k_mlp<<<dim3(B), b256, 0, stream>>>(
        pooled, vrow, roots, td_w2, td_b2, bu_w2, bu_b2,
        p_w1, p_b1, p_w2, p_b2, out, B);
}